// Round 1
// baseline (179.219 us; speedup 1.0000x reference)
//
#include <hip/hip_runtime.h>
#include <hip/hip_bf16.h>
#include <stdint.h>

#define D_EMB 128
#define D_NLP 768
#define BM 64
#define BK 64
#define NKC (D_NLP / BK)   // 12 k-chunks

typedef __attribute__((ext_vector_type(8))) short bf16x8;
typedef __attribute__((ext_vector_type(4))) float f32x4;
typedef __attribute__((ext_vector_type(8))) unsigned short u16x8;

__device__ __forceinline__ unsigned short f2bf(float f) {
  unsigned u = __builtin_bit_cast(unsigned, f);
  u += 0x7fffu + ((u >> 16) & 1u);   // RTNE (NaN-free inputs)
  return (unsigned short)(u >> 16);
}

// ---- kernel W: convert w0 (128x768 f32) -> bf16, pre-swizzled per k-chunk so a
// linear LDS copy yields the XOR-swizzled layout the MFMA ds_reads expect.
__global__ void kw(const float* __restrict__ w0, unsigned short* __restrict__ w0s) {
  int t = blockIdx.x * 256 + threadIdx.x;       // 12288 threads total
  if (t >= (D_EMB * D_NLP) / 8) return;
  int u = t & 7, row = (t >> 3) & 127, kc = t >> 10;
  const float4* src = (const float4*)(w0 + (size_t)row * D_NLP + kc * BK + ((u ^ (row & 7)) * 8));
  float4 v0 = src[0], v1 = src[1];
  u16x8 o;
  o[0] = f2bf(v0.x); o[1] = f2bf(v0.y); o[2] = f2bf(v0.z); o[3] = f2bf(v0.w);
  o[4] = f2bf(v1.x); o[5] = f2bf(v1.y); o[6] = f2bf(v1.z); o[7] = f2bf(v1.w);
  *(u16x8*)(w0s + (size_t)t * 8) = o;
}

// ---- kernel M: mn = min_e max(ei[0][e], ei[1][e])
__global__ void km(const int* __restrict__ ei, int E, int* __restrict__ mn) {
  int t = blockIdx.x * blockDim.x + threadIdx.x;
  int stride = gridDim.x * blockDim.x;
  int m = 0x7fffffff;
  for (int e = t; e < E; e += stride) {
    int a = ei[e], b = ei[E + e];
    int q = a > b ? a : b;
    m = q < m ? q : m;
  }
  #pragma unroll
  for (int off = 32; off; off >>= 1) {
    int o = __shfl_xor(m, off);
    m = o < m ? o : m;
  }
  if ((threadIdx.x & 63) == 0) atomicMin(mn, m);
}

// ---- kernel T: t_a[n] = z[n].w1a, t_b[n] = z[n].w1b   (one wave per node)
__global__ void kt(const float* __restrict__ z, const float* __restrict__ w1,
                   float* __restrict__ ta, float* __restrict__ tb, int N) {
  int n = blockIdx.x * 4 + (threadIdx.x >> 6);
  int lane = threadIdx.x & 63;
  if (n >= N) return;
  float2 zv = *(const float2*)(z + (size_t)n * D_EMB + lane * 2);
  float2 wa = *(const float2*)(w1 + lane * 2);
  float2 wb = *(const float2*)(w1 + D_EMB + lane * 2);
  float pa = zv.x * wa.x + zv.y * wa.y;
  float pb = zv.x * wb.x + zv.y * wb.y;
  #pragma unroll
  for (int off = 32; off; off >>= 1) {
    pa += __shfl_xor(pa, off);
    pb += __shfl_xor(pb, off);
  }
  if (lane == 0) { ta[n] = pa; tb[n] = pb; }
}

// ---- kernel C: s[n] = sum_d prelu(z0[n] . w0[d,:]) * w1c[d]  via bf16 MFMA.
// BM=64 rows/block (4 waves x 16 rows), BK=64, double-buffered LDS, reg-staged
// f32->bf16 conversion for A, pre-swizzled bf16 w0 for B.
__global__ __launch_bounds__(256) void kc(
    const float* __restrict__ z0, const unsigned short* __restrict__ w0s,
    const float* __restrict__ w1, const float* __restrict__ prelu_a,
    float* __restrict__ sv, int N) {
  __shared__ unsigned short Ab[2][BM * BK];      // 8KB x2
  __shared__ unsigned short Bb[2][D_EMB * BK];   // 16KB x2

  const int tid = threadIdx.x;
  const int lane = tid & 63;
  const int wave = tid >> 6;
  const int r0 = blockIdx.x * BM;

  // A staging: thread covers rows (tid>>3) and (tid>>3)+32, 16B-unit u = tid&7
  const int sa_row = tid >> 3;
  const int sa_u = tid & 7;
  const size_t gr0 = (size_t)min(r0 + sa_row, N - 1);
  const size_t gr1 = (size_t)min(r0 + sa_row + 32, N - 1);
  const float* aSrc0 = z0 + gr0 * D_NLP + sa_u * 8;
  const float* aSrc1 = z0 + gr1 * D_NLP + sa_u * 8;
  const int aw0 = (sa_row * 8 + (sa_u ^ (sa_row & 7))) * 8;          // ushort idx
  const int aw1 = ((sa_row + 32) * 8 + (sa_u ^ (sa_row & 7))) * 8;   // (r+32)&7 == r&7

  float a_reg[16];
  uint4 b_reg[4];
  f32x4 acc[8];
  #pragma unroll
  for (int c = 0; c < 8; ++c) acc[c] = (f32x4){0.f, 0.f, 0.f, 0.f};

  auto load_g = [&](int kc_) {
    const float4* f0 = (const float4*)(aSrc0 + kc_ * BK);
    const float4* f1 = (const float4*)(aSrc1 + kc_ * BK);
    float4 v;
    v = f0[0]; a_reg[0] = v.x; a_reg[1] = v.y; a_reg[2]  = v.z; a_reg[3]  = v.w;
    v = f0[1]; a_reg[4] = v.x; a_reg[5] = v.y; a_reg[6]  = v.z; a_reg[7]  = v.w;
    v = f1[0]; a_reg[8] = v.x; a_reg[9] = v.y; a_reg[10] = v.z; a_reg[11] = v.w;
    v = f1[1]; a_reg[12] = v.x; a_reg[13] = v.y; a_reg[14] = v.z; a_reg[15] = v.w;
    const uint4* bsrc = (const uint4*)(w0s + (size_t)kc_ * (D_EMB * BK));
    #pragma unroll
    for (int p = 0; p < 4; ++p) b_reg[p] = bsrc[tid + p * 256];
  };

  auto write_lds = [&](int buf) {
    u16x8 v;
    #pragma unroll
    for (int j = 0; j < 8; ++j) v[j] = f2bf(a_reg[j]);
    *(u16x8*)&Ab[buf][aw0] = v;
    #pragma unroll
    for (int j = 0; j < 8; ++j) v[j] = f2bf(a_reg[8 + j]);
    *(u16x8*)&Ab[buf][aw1] = v;
    #pragma unroll
    for (int p = 0; p < 4; ++p)
      *(uint4*)&Bb[buf][(tid + p * 256) * 8] = b_reg[p];
  };

  const int arow = wave * 16 + (lane & 15);
  const int kg = lane >> 4;

  auto compute = [&](int buf) {
    #pragma unroll
    for (int ks = 0; ks < 2; ++ks) {
      bf16x8 af = *(const bf16x8*)&Ab[buf][(arow * 8 + ((ks * 4 + kg) ^ (arow & 7))) * 8];
      #pragma unroll
      for (int c = 0; c < 8; ++c) {
        int brow = c * 16 + (lane & 15);
        bf16x8 bfr = *(const bf16x8*)&Bb[buf][(brow * 8 + ((ks * 4 + kg) ^ (brow & 7))) * 8];
        acc[c] = __builtin_amdgcn_mfma_f32_16x16x32_bf16(af, bfr, acc[c], 0, 0, 0);
      }
    }
  };

  load_g(0);
  write_lds(0);
  __syncthreads();
  for (int t = 0; t < NKC; ++t) {
    if (t + 1 < NKC) load_g(t + 1);
    compute(t & 1);
    if (t + 1 < NKC) write_lds((t + 1) & 1);
    __syncthreads();
  }

  // epilogue: prelu + * w1c[col], reduce over the 16 cols held per lane-group
  float ap = prelu_a[0];
  float ssum[4] = {0.f, 0.f, 0.f, 0.f};
  #pragma unroll
  for (int c = 0; c < 8; ++c) {
    float wc = w1[2 * D_EMB + c * 16 + (lane & 15)];
    #pragma unroll
    for (int i = 0; i < 4; ++i) {
      float h = acc[c][i];
      float x = h >= 0.f ? h : ap * h;
      ssum[i] += x * wc;
    }
  }
  #pragma unroll
  for (int off = 1; off < 16; off <<= 1) {
    #pragma unroll
    for (int i = 0; i < 4; ++i) ssum[i] += __shfl_xor(ssum[i], off);
  }
  if ((lane & 15) == 0) {
    int rbase = r0 + wave * 16 + (lane >> 4) * 4;
    #pragma unroll
    for (int i = 0; i < 4; ++i) {
      int r = rbase + i;
      if (r < N) sv[r] = ssum[i];
    }
  }
}

// ---- kernel D: per-edge gather + add
__global__ void kd(const int* __restrict__ ei, const int* __restrict__ mn,
                   const float* __restrict__ ta, const float* __restrict__ tb,
                   const float* __restrict__ sv, const float* __restrict__ b1,
                   float* __restrict__ out, int E) {
  int e = blockIdx.x * blockDim.x + threadIdx.x;
  if (e >= E) return;
  int i0 = ei[e], i1 = ei[E + e];
  int q = (i0 > i1 ? i0 : i1) - mn[0];
  out[e] = ta[i0] + tb[i1] + sv[q] + b1[0];
}

extern "C" void kernel_launch(void* const* d_in, const int* in_sizes, int n_in,
                              void* d_out, int out_size, void* d_ws, size_t ws_size,
                              hipStream_t stream) {
  const float* z  = (const float*)d_in[0];
  const float* z0 = (const float*)d_in[1];
  const int*   ei = (const int*)d_in[2];
  const float* w0 = (const float*)d_in[3];
  const float* pa = (const float*)d_in[4];
  const float* w1 = (const float*)d_in[5];
  const float* b1 = (const float*)d_in[6];
  float* out = (float*)d_out;
  const int N = in_sizes[0] / D_EMB;
  const int E = in_sizes[2] / 2;

  // workspace layout (needs ~1.4 MB):
  // [0,4)        mn
  // [256,196864) w0 as bf16, pre-swizzled
  // then ta[N], tb[N], sv[N] (f32)
  char* ws = (char*)d_ws;
  int* mn = (int*)ws;
  unsigned short* w0s = (unsigned short*)(ws + 256);
  float* ta = (float*)(ws + 256 + 196608);
  float* tb = ta + N;
  float* sv = tb + N;

  hipMemsetAsync(mn, 0x7f, 4, stream);                       // 0x7f7f7f7f > N
  kw<<<(D_EMB * D_NLP / 8 + 255) / 256, 256, 0, stream>>>(w0, w0s);
  km<<<256, 256, 0, stream>>>(ei, E, mn);
  kt<<<(N + 3) / 4, 256, 0, stream>>>(z, w1, ta, tb, N);
  kc<<<(N + BM - 1) / BM, 256, 0, stream>>>(z0, w0s, w1, pa, sv, N);
  kd<<<(E + 255) / 256, 256, 0, stream>>>(ei, mn, ta, tb, sv, b1, out, E);
}

// Round 2
// 136.588 us; speedup vs baseline: 1.3121x; 1.3121x over previous
//
#include <hip/hip_runtime.h>
#include <hip/hip_bf16.h>
#include <stdint.h>

#define D_EMB 128
#define D_NLP 768
#define BM 64
#define BK 64
#define NKC (D_NLP / BK)   // 12 k-chunks

typedef __attribute__((ext_vector_type(8))) short bf16x8;
typedef __attribute__((ext_vector_type(4))) float f32x4;
typedef __attribute__((ext_vector_type(8))) unsigned short u16x8;

__device__ __forceinline__ unsigned short f2bf(float f) {
  unsigned u = __builtin_bit_cast(unsigned, f);
  u += 0x7fffu + ((u >> 16) & 1u);   // RTNE (NaN-free inputs)
  return (unsigned short)(u >> 16);
}

// ---- kernel W: convert w0 (128x768 f32) -> bf16, pre-swizzled per k-chunk so a
// linear lane-order copy (global_load_lds) yields the XOR-swizzled LDS layout.
__global__ void kw(const float* __restrict__ w0, unsigned short* __restrict__ w0s) {
  int t = blockIdx.x * 256 + threadIdx.x;       // 12288 threads total
  if (t >= (D_EMB * D_NLP) / 8) return;
  int u = t & 7, row = (t >> 3) & 127, kc = t >> 10;
  const float4* src = (const float4*)(w0 + (size_t)row * D_NLP + kc * BK + ((u ^ (row & 7)) * 8));
  float4 v0 = src[0], v1 = src[1];
  u16x8 o;
  o[0] = f2bf(v0.x); o[1] = f2bf(v0.y); o[2] = f2bf(v0.z); o[3] = f2bf(v0.w);
  o[4] = f2bf(v1.x); o[5] = f2bf(v1.y); o[6] = f2bf(v1.z); o[7] = f2bf(v1.w);
  *(u16x8*)(w0s + (size_t)t * 8) = o;
}

// ---- kernel M: mn = min_e max(ei[0][e], ei[1][e])
__global__ void km(const int* __restrict__ ei, int E, int* __restrict__ mn) {
  int t = blockIdx.x * blockDim.x + threadIdx.x;
  int stride = gridDim.x * blockDim.x;
  int m = 0x7fffffff;
  for (int e = t; e < E; e += stride) {
    int a = ei[e], b = ei[E + e];
    int q = a > b ? a : b;
    m = q < m ? q : m;
  }
  #pragma unroll
  for (int off = 32; off; off >>= 1) {
    int o = __shfl_xor(m, off);
    m = o < m ? o : m;
  }
  if ((threadIdx.x & 63) == 0) atomicMin(mn, m);
}

// ---- kernel T: t_a[n] = z[n].w1a, t_b[n] = z[n].w1b   (one wave per node)
__global__ void kt(const float* __restrict__ z, const float* __restrict__ w1,
                   float* __restrict__ ta, float* __restrict__ tb, int N) {
  int n = blockIdx.x * 4 + (threadIdx.x >> 6);
  int lane = threadIdx.x & 63;
  if (n >= N) return;
  float2 zv = *(const float2*)(z + (size_t)n * D_EMB + lane * 2);
  float2 wa = *(const float2*)(w1 + lane * 2);
  float2 wb = *(const float2*)(w1 + D_EMB + lane * 2);
  float pa = zv.x * wa.x + zv.y * wa.y;
  float pb = zv.x * wb.x + zv.y * wb.y;
  #pragma unroll
  for (int off = 32; off; off >>= 1) {
    pa += __shfl_xor(pa, off);
    pb += __shfl_xor(pb, off);
  }
  if (lane == 0) { ta[n] = pa; tb[n] = pb; }
}

// ---- kernel C: s[n] = sum_d prelu(z0[n] . w0[d,:]) * w1c[d]  via bf16 MFMA.
// A fragments: loaded DIRECTLY global->reg (layout row=lane&15, k=(lane>>4)*8+j),
// converted f32->bf16 in-register, prefetched one chunk ahead. No A staging.
// B: bf16 pre-swizzled in ws, staged via global_load_lds (16B), double-buffered.
// LDS = 32KB -> 5 blocks/CU for latency hiding.
__global__ __launch_bounds__(256) void kc(
    const float* __restrict__ z0, const unsigned short* __restrict__ w0s,
    const float* __restrict__ w1, const float* __restrict__ prelu_a,
    float* __restrict__ sv, int N) {
  __shared__ unsigned short Bb[2][D_EMB * BK];   // 16KB x2

  const int tid = threadIdx.x;
  const int lane = tid & 63;
  const int wave = tid >> 6;
  const int r0 = blockIdx.x * BM;
  const int kg = lane >> 4;
  const int arow_g = min(r0 + wave * 16 + (lane & 15), N - 1);
  const float* aBase = z0 + (size_t)arow_g * D_NLP + kg * 8;

  f32x4 acc[8];
  #pragma unroll
  for (int c = 0; c < 8; ++c) acc[c] = (f32x4){0.f, 0.f, 0.f, 0.f};

  float4 fa[4];
  bf16x8 af[2];

  auto loadA = [&](int t) {
    const float4* p0 = (const float4*)(aBase + t * BK);        // ks=0: k in [0,8)+kg*8
    const float4* p1 = (const float4*)(aBase + t * BK + 32);   // ks=1
    fa[0] = p0[0]; fa[1] = p0[1]; fa[2] = p1[0]; fa[3] = p1[1];
  };

  auto cvtA = [&]() {
    u16x8 v;
    v[0] = f2bf(fa[0].x); v[1] = f2bf(fa[0].y); v[2] = f2bf(fa[0].z); v[3] = f2bf(fa[0].w);
    v[4] = f2bf(fa[1].x); v[5] = f2bf(fa[1].y); v[6] = f2bf(fa[1].z); v[7] = f2bf(fa[1].w);
    af[0] = __builtin_bit_cast(bf16x8, v);
    v[0] = f2bf(fa[2].x); v[1] = f2bf(fa[2].y); v[2] = f2bf(fa[2].z); v[3] = f2bf(fa[2].w);
    v[4] = f2bf(fa[3].x); v[5] = f2bf(fa[3].y); v[6] = f2bf(fa[3].z); v[7] = f2bf(fa[3].w);
    af[1] = __builtin_bit_cast(bf16x8, v);
  };

  auto stageB = [&](int t, int buf) {
    const unsigned short* g = w0s + (size_t)t * (D_EMB * BK) + (size_t)tid * 8;
    #pragma unroll
    for (int p = 0; p < 4; ++p) {
      __builtin_amdgcn_global_load_lds(
          (const __attribute__((address_space(1))) void*)(g + p * 256 * 8),
          (__attribute__((address_space(3))) void*)&Bb[buf][(wave * 64 + p * 256) * 8],
          16, 0, 0);
    }
  };

  auto compute = [&](int buf) {
    #pragma unroll
    for (int ks = 0; ks < 2; ++ks) {
      #pragma unroll
      for (int c = 0; c < 8; ++c) {
        int brow = c * 16 + (lane & 15);
        bf16x8 bfr = *(const bf16x8*)&Bb[buf][(brow * 8 + ((ks * 4 + kg) ^ (brow & 7))) * 8];
        acc[c] = __builtin_amdgcn_mfma_f32_16x16x32_bf16(af[ks], bfr, acc[c], 0, 0, 0);
      }
    }
  };

  loadA(0);
  stageB(0, 0);
  __syncthreads();                      // drains vmcnt -> fa(0), Bb[0] ready
  for (int t = 0; t < NKC; ++t) {
    cvtA();                             // consume fa (chunk t) before reload
    if (t + 1 < NKC) { loadA(t + 1); stageB(t + 1, (t + 1) & 1); }
    compute(t & 1);
    __syncthreads();
  }

  // epilogue: prelu + * w1c[col], reduce over the 16 cols held per lane-group
  float ap = prelu_a[0];
  float ssum[4] = {0.f, 0.f, 0.f, 0.f};
  #pragma unroll
  for (int c = 0; c < 8; ++c) {
    float wc = w1[2 * D_EMB + c * 16 + (lane & 15)];
    #pragma unroll
    for (int i = 0; i < 4; ++i) {
      float h = acc[c][i];
      float x = h >= 0.f ? h : ap * h;
      ssum[i] += x * wc;
    }
  }
  #pragma unroll
  for (int off = 1; off < 16; off <<= 1) {
    #pragma unroll
    for (int i = 0; i < 4; ++i) ssum[i] += __shfl_xor(ssum[i], off);
  }
  if ((lane & 15) == 0) {
    int rbase = r0 + wave * 16 + (lane >> 4) * 4;
    #pragma unroll
    for (int i = 0; i < 4; ++i) {
      int r = rbase + i;
      if (r < N) sv[r] = ssum[i];
    }
  }
}

// ---- kernel D: per-edge gather + add
__global__ void kd(const int* __restrict__ ei, const int* __restrict__ mn,
                   const float* __restrict__ ta, const float* __restrict__ tb,
                   const float* __restrict__ sv, const float* __restrict__ b1,
                   float* __restrict__ out, int E) {
  int e = blockIdx.x * blockDim.x + threadIdx.x;
  if (e >= E) return;
  int i0 = ei[e], i1 = ei[E + e];
  int q = (i0 > i1 ? i0 : i1) - mn[0];
  out[e] = ta[i0] + tb[i1] + sv[q] + b1[0];
}

extern "C" void kernel_launch(void* const* d_in, const int* in_sizes, int n_in,
                              void* d_out, int out_size, void* d_ws, size_t ws_size,
                              hipStream_t stream) {
  const float* z  = (const float*)d_in[0];
  const float* z0 = (const float*)d_in[1];
  const int*   ei = (const int*)d_in[2];
  const float* w0 = (const float*)d_in[3];
  const float* pa = (const float*)d_in[4];
  const float* w1 = (const float*)d_in[5];
  const float* b1 = (const float*)d_in[6];
  float* out = (float*)d_out;
  const int N = in_sizes[0] / D_EMB;
  const int E = in_sizes[2] / 2;

  // workspace layout (~1.4 MB):
  // [0,4) mn | [256, 256+196608) w0 bf16 pre-swizzled | ta[N], tb[N], sv[N] f32
  char* ws = (char*)d_ws;
  int* mn = (int*)ws;
  unsigned short* w0s = (unsigned short*)(ws + 256);
  float* ta = (float*)(ws + 256 + 196608);
  float* tb = ta + N;
  float* sv = tb + N;

  hipMemsetAsync(mn, 0x7f, 4, stream);                       // 0x7f7f7f7f > N
  kw<<<(D_EMB * D_NLP / 8 + 255) / 256, 256, 0, stream>>>(w0, w0s);
  km<<<256, 256, 0, stream>>>(ei, E, mn);
  kt<<<(N + 3) / 4, 256, 0, stream>>>(z, w1, ta, tb, N);
  kc<<<(N + BM - 1) / BM, 256, 0, stream>>>(z0, w0s, w1, pa, sv, N);
  kd<<<(E + 255) / 256, 256, 0, stream>>>(ei, mn, ta, tb, sv, b1, out, E);
}

// Round 3
// 127.524 us; speedup vs baseline: 1.4054x; 1.0711x over previous
//
#include <hip/hip_runtime.h>
#include <hip/hip_bf16.h>
#include <stdint.h>

#define D_EMB 128
#define D_NLP 768
#define BM 64
#define BK 64
#define NKC (D_NLP / BK)   // 12 k-chunks

typedef __attribute__((ext_vector_type(8))) short bf16x8;
typedef __attribute__((ext_vector_type(4))) float f32x4;
typedef __attribute__((ext_vector_type(8))) unsigned short u16x8;

__device__ __forceinline__ unsigned short f2bf(float f) {
  unsigned u = __builtin_bit_cast(unsigned, f);
  u += 0x7fffu + ((u >> 16) & 1u);   // RTNE (NaN-free inputs)
  return (unsigned short)(u >> 16);
}

// ---- kernel W: w0 (128x768 f32) -> bf16, pre-swizzled per k-chunk so a linear
// lane-order copy (global_load_lds) yields the XOR-swizzled LDS layout.
// Also initializes mn (replaces a hipMemsetAsync dispatch).
__global__ void kw(const float* __restrict__ w0, unsigned short* __restrict__ w0s,
                   int* __restrict__ mn) {
  if (blockIdx.x == 0 && threadIdx.x == 0) mn[0] = 0x7fffffff;
  int t = blockIdx.x * 256 + threadIdx.x;       // 12288 threads total
  if (t >= (D_EMB * D_NLP) / 8) return;
  int u = t & 7, row = (t >> 3) & 127, kc = t >> 10;
  const float4* src = (const float4*)(w0 + (size_t)row * D_NLP + kc * BK + ((u ^ (row & 7)) * 8));
  float4 v0 = src[0], v1 = src[1];
  u16x8 o;
  o[0] = f2bf(v0.x); o[1] = f2bf(v0.y); o[2] = f2bf(v0.z); o[3] = f2bf(v0.w);
  o[4] = f2bf(v1.x); o[5] = f2bf(v1.y); o[6] = f2bf(v1.z); o[7] = f2bf(v1.w);
  *(u16x8*)(w0s + (size_t)t * 8) = o;
}

// ---- kernel M: mn = min_e max(ei[0][e], ei[1][e])
__global__ void km(const int* __restrict__ ei, int E, int* __restrict__ mn) {
  int t = blockIdx.x * blockDim.x + threadIdx.x;
  int stride = gridDim.x * blockDim.x;
  int m = 0x7fffffff;
  for (int e = t; e < E; e += stride) {
    int a = ei[e], b = ei[E + e];
    int q = a > b ? a : b;
    m = q < m ? q : m;
  }
  #pragma unroll
  for (int off = 32; off; off >>= 1) {
    int o = __shfl_xor(m, off);
    m = o < m ? o : m;
  }
  if ((threadIdx.x & 63) == 0) atomicMin(mn, m);
}

// ---- kernel C (fused): per 64-node tile:
//   sv[n] = sum_d prelu(z0[n].w0[d,:]) * w1c[d]   (bf16 MFMA, A global->reg,
//           B via global_load_lds from pre-swizzled bf16 w0s, double-buffered)
//   ta[n] = z[n].w1a, tb[n] = z[n].w1b            (tail phase, same lane->row map)
__global__ __launch_bounds__(256) void kc(
    const float* __restrict__ z0, const float* __restrict__ z,
    const unsigned short* __restrict__ w0s, const float* __restrict__ w1,
    const float* __restrict__ prelu_a, float* __restrict__ sv,
    float* __restrict__ ta, float* __restrict__ tb, int N) {
  __shared__ unsigned short Bb[2][D_EMB * BK];   // 16KB x2

  const int tid = threadIdx.x;
  const int lane = tid & 63;
  const int wave = tid >> 6;
  const int r0 = blockIdx.x * BM;
  const int kg = lane >> 4;
  const int myrow = r0 + wave * 16 + (lane & 15);
  const int arow_g = min(myrow, N - 1);
  const float* aBase = z0 + (size_t)arow_g * D_NLP + kg * 8;

  f32x4 acc[8];
  #pragma unroll
  for (int c = 0; c < 8; ++c) acc[c] = (f32x4){0.f, 0.f, 0.f, 0.f};

  float4 fa[4];
  bf16x8 af[2];

  auto loadA = [&](int t) {
    const float4* p0 = (const float4*)(aBase + t * BK);        // ks=0
    const float4* p1 = (const float4*)(aBase + t * BK + 32);   // ks=1
    fa[0] = p0[0]; fa[1] = p0[1]; fa[2] = p1[0]; fa[3] = p1[1];
  };

  auto cvtA = [&]() {
    u16x8 v;
    v[0] = f2bf(fa[0].x); v[1] = f2bf(fa[0].y); v[2] = f2bf(fa[0].z); v[3] = f2bf(fa[0].w);
    v[4] = f2bf(fa[1].x); v[5] = f2bf(fa[1].y); v[6] = f2bf(fa[1].z); v[7] = f2bf(fa[1].w);
    af[0] = __builtin_bit_cast(bf16x8, v);
    v[0] = f2bf(fa[2].x); v[1] = f2bf(fa[2].y); v[2] = f2bf(fa[2].z); v[3] = f2bf(fa[2].w);
    v[4] = f2bf(fa[3].x); v[5] = f2bf(fa[3].y); v[6] = f2bf(fa[3].z); v[7] = f2bf(fa[3].w);
    af[1] = __builtin_bit_cast(bf16x8, v);
  };

  auto stageB = [&](int t, int buf) {
    const unsigned short* g = w0s + (size_t)t * (D_EMB * BK) + (size_t)tid * 8;
    #pragma unroll
    for (int p = 0; p < 4; ++p) {
      __builtin_amdgcn_global_load_lds(
          (const __attribute__((address_space(1))) void*)(g + p * 256 * 8),
          (__attribute__((address_space(3))) void*)&Bb[buf][(wave * 64 + p * 256) * 8],
          16, 0, 0);
    }
  };

  auto compute = [&](int buf) {
    #pragma unroll
    for (int ks = 0; ks < 2; ++ks) {
      #pragma unroll
      for (int c = 0; c < 8; ++c) {
        int brow = c * 16 + (lane & 15);
        bf16x8 bfr = *(const bf16x8*)&Bb[buf][(brow * 8 + ((ks * 4 + kg) ^ (brow & 7))) * 8];
        acc[c] = __builtin_amdgcn_mfma_f32_16x16x32_bf16(af[ks], bfr, acc[c], 0, 0, 0);
      }
    }
  };

  loadA(0);
  stageB(0, 0);
  __syncthreads();                      // fa(0), Bb[0] ready
  for (int t = 0; t < NKC; ++t) {
    cvtA();                             // consume fa (chunk t) before reload
    if (t + 1 < NKC) { loadA(t + 1); stageB(t + 1, (t + 1) & 1); }
    compute(t & 1);
    __syncthreads();
  }

  // epilogue 1: prelu + * w1c[col], reduce over the 16 cols held per lane-group
  float ap = prelu_a[0];
  float ssum[4] = {0.f, 0.f, 0.f, 0.f};
  #pragma unroll
  for (int c = 0; c < 8; ++c) {
    float wc = w1[2 * D_EMB + c * 16 + (lane & 15)];
    #pragma unroll
    for (int i = 0; i < 4; ++i) {
      float h = acc[c][i];
      float x = h >= 0.f ? h : ap * h;
      ssum[i] += x * wc;
    }
  }
  #pragma unroll
  for (int off = 1; off < 16; off <<= 1) {
    #pragma unroll
    for (int i = 0; i < 4; ++i) ssum[i] += __shfl_xor(ssum[i], off);
  }
  if ((lane & 15) == 0) {
    int rbase = r0 + wave * 16 + (lane >> 4) * 4;
    #pragma unroll
    for (int i = 0; i < 4; ++i) {
      int r = rbase + i;
      if (r < N) sv[r] = ssum[i];
    }
  }

  // epilogue 2 (fused kt): ta/tb for this block's 64 rows.
  // lane -> row = lane&15 (same as A), kg covers 32 consecutive floats.
  {
    const float* zp = z + (size_t)arow_g * D_EMB + kg * 32;
    const float4* wa4 = (const float4*)(w1 + kg * 32);
    const float4* wb4 = (const float4*)(w1 + D_EMB + kg * 32);
    float pa = 0.f, pb = 0.f;
    #pragma unroll
    for (int i = 0; i < 8; ++i) {
      float4 zv = ((const float4*)zp)[i];
      float4 wa = wa4[i];
      float4 wb = wb4[i];
      pa += zv.x * wa.x + zv.y * wa.y + zv.z * wa.z + zv.w * wa.w;
      pb += zv.x * wb.x + zv.y * wb.y + zv.z * wb.z + zv.w * wb.w;
    }
    pa += __shfl_xor(pa, 16); pa += __shfl_xor(pa, 32);
    pb += __shfl_xor(pb, 16); pb += __shfl_xor(pb, 32);
    if (kg == 0 && myrow < N) { ta[myrow] = pa; tb[myrow] = pb; }
  }
}

// ---- kernel D: per-edge gather + add
__global__ void kd(const int* __restrict__ ei, const int* __restrict__ mn,
                   const float* __restrict__ ta, const float* __restrict__ tb,
                   const float* __restrict__ sv, const float* __restrict__ b1,
                   float* __restrict__ out, int E) {
  int e = blockIdx.x * blockDim.x + threadIdx.x;
  if (e >= E) return;
  int i0 = ei[e], i1 = ei[E + e];
  int q = (i0 > i1 ? i0 : i1) - mn[0];
  out[e] = ta[i0] + tb[i1] + sv[q] + b1[0];
}

extern "C" void kernel_launch(void* const* d_in, const int* in_sizes, int n_in,
                              void* d_out, int out_size, void* d_ws, size_t ws_size,
                              hipStream_t stream) {
  const float* z  = (const float*)d_in[0];
  const float* z0 = (const float*)d_in[1];
  const int*   ei = (const int*)d_in[2];
  const float* w0 = (const float*)d_in[3];
  const float* pa = (const float*)d_in[4];
  const float* w1 = (const float*)d_in[5];
  const float* b1 = (const float*)d_in[6];
  float* out = (float*)d_out;
  const int N = in_sizes[0] / D_EMB;
  const int E = in_sizes[2] / 2;

  // workspace layout (~1.4 MB):
  // [0,4) mn | [256, 256+196608) w0 bf16 pre-swizzled | ta[N], tb[N], sv[N] f32
  char* ws = (char*)d_ws;
  int* mn = (int*)ws;
  unsigned short* w0s = (unsigned short*)(ws + 256);
  float* ta = (float*)(ws + 256 + 196608);
  float* tb = ta + N;
  float* sv = tb + N;

  kw<<<(D_EMB * D_NLP / 8 + 255) / 256, 256, 0, stream>>>(w0, w0s, mn);
  km<<<256, 256, 0, stream>>>(ei, E, mn);
  kc<<<(N + BM - 1) / BM, 256, 0, stream>>>(z0, z, w0s, w1, pa, sv, ta, tb, N);
  kd<<<(E + 255) / 256, 256, 0, stream>>>(ei, mn, ta, tb, sv, b1, out, E);
}